// Round 1
// baseline (18459.550 us; speedup 1.0000x reference)
//
#include <hip/hip_runtime.h>
#include <math.h>

// 2-layer LSTM, B=64, T=512, F=256, H=512, fp32.
// Wavefront schedule: macro-step s runs layer0@t=s and layer1@t=s-1 in one launch.
// Grid: 256 blocks x 512 threads.
//   blocks [0,128):  layer0, tile = blockIdx.x,    4 hidden units (16 gate cols)
//   blocks [128,256): layer1, tile = blockIdx.x-128
// Within a block: 8 waves split the K dimension; lane = batch index b.
// Weights are read at wave-uniform addresses (readfirstlane on wave id) so the
// compiler can scalarize them (s_load) -> no LDS tiling needed for W.
// h state lives in ws, transposed+4-blocked: hT[k/4][b][4] so lanes load float4
// coalesced. Cross-wave partial-gate reduction via LDS atomicAdd, then fused
// activations + c/h update.

#define TT 512
#define FF 256
#define HH 512

__device__ __forceinline__ float sigmoidf_(float v) {
    return 1.0f / (1.0f + __expf(-v));
}

__global__ void __launch_bounds__(512) lstm_step(
    const int s,
    const float* __restrict__ x,
    const float* __restrict__ Wih0, const float* __restrict__ Whh0,
    const float* __restrict__ bi0,  const float* __restrict__ bh0,
    const float* __restrict__ Wih1, const float* __restrict__ Whh1,
    const float* __restrict__ bi1,  const float* __restrict__ bh1,
    float* __restrict__ h0T, float* __restrict__ c0,
    float* __restrict__ h1T, float* __restrict__ c1,
    float* __restrict__ out)
{
    const int layer = blockIdx.x >> 7;
    const int tile  = blockIdx.x & 127;
    if (layer == 0 && s >= TT) return;   // last macro-step: only layer1 works
    if (layer == 1 && s == 0)  return;   // first macro-step: only layer0 works
    const int t  = layer ? (s - 1) : s;
    const int ub = tile << 2;            // 4 hidden units per block
    const int tid  = threadIdx.x;
    const int lane = tid & 63;           // = batch index b
    const int wv   = __builtin_amdgcn_readfirstlane(tid >> 6);  // wave id 0..7 (uniform)

    __shared__ float gsh[16][64];        // [g*4+ul][b] gate pre-activations

    // init with biases
    const float* bi = layer ? bi1 : bi0;
    const float* bh = layer ? bh1 : bh0;
    for (int q = tid; q < 16 * 64; q += 512) {
        const int jj = q >> 6, b = q & 63;
        const int jg = ((jj >> 2) << 9) + ub + (jj & 3);   // g*512 + u
        gsh[jj][b] = bi[jg] + bh[jg];
    }

    float acc[16];
#pragma unroll
    for (int j = 0; j < 16; ++j) acc[j] = 0.0f;

    if (layer == 0) {
        // ---- segment 1: x_t @ Wih0^T, K=256; this wave: k in [wv*32, wv*32+32)
        const float* xrow = x + ((size_t)lane * TT + t) * FF;
        const int kx0 = wv * 32;
        for (int kc = 0; kc < 32; kc += 4) {
            const int k = kx0 + kc;
            const float4 hv = *(const float4*)(xrow + k);
#pragma unroll
            for (int j = 0; j < 16; ++j) {
                const int jg = ((j >> 2) << 9) + ub + (j & 3);
                const float* wr = Wih0 + (size_t)jg * FF + k;   // uniform -> s_load
                acc[j] = fmaf(hv.x, wr[0], acc[j]);
                acc[j] = fmaf(hv.y, wr[1], acc[j]);
                acc[j] = fmaf(hv.z, wr[2], acc[j]);
                acc[j] = fmaf(hv.w, wr[3], acc[j]);
            }
        }
        // ---- segment 2: h0[t-1] @ Whh0^T, K=512; this wave: [wv*64, +64)
        const float* hsrc = h0T + (((t + 1) & 1) << 15);   // ping-pong 32768 floats
        const int kh0 = wv * 64;
        for (int kc = 0; kc < 64; kc += 4) {
            const int k = kh0 + kc;
            const float4 hv = *(const float4*)(hsrc + ((k >> 2) << 8) + (lane << 2));
#pragma unroll
            for (int j = 0; j < 16; ++j) {
                const int jg = ((j >> 2) << 9) + ub + (j & 3);
                const float* wr = Whh0 + (size_t)jg * HH + k;
                acc[j] = fmaf(hv.x, wr[0], acc[j]);
                acc[j] = fmaf(hv.y, wr[1], acc[j]);
                acc[j] = fmaf(hv.z, wr[2], acc[j]);
                acc[j] = fmaf(hv.w, wr[3], acc[j]);
            }
        }
    } else {
        // layer 1 @ t=s-1: input = h0[t], hidden = h1[t-1]
        const float* hin   = h0T + (((s - 1) & 1) << 15);  // h0[t], written at macro-step s-1
        const float* hprev = h1T + ((s & 1) << 15);        // h1[t-1]
        const int kh0 = wv * 64;
        for (int kc = 0; kc < 64; kc += 4) {
            const int k = kh0 + kc;
            const float4 hv = *(const float4*)(hin + ((k >> 2) << 8) + (lane << 2));
#pragma unroll
            for (int j = 0; j < 16; ++j) {
                const int jg = ((j >> 2) << 9) + ub + (j & 3);
                const float* wr = Wih1 + (size_t)jg * HH + k;
                acc[j] = fmaf(hv.x, wr[0], acc[j]);
                acc[j] = fmaf(hv.y, wr[1], acc[j]);
                acc[j] = fmaf(hv.z, wr[2], acc[j]);
                acc[j] = fmaf(hv.w, wr[3], acc[j]);
            }
        }
        for (int kc = 0; kc < 64; kc += 4) {
            const int k = kh0 + kc;
            const float4 hv = *(const float4*)(hprev + ((k >> 2) << 8) + (lane << 2));
#pragma unroll
            for (int j = 0; j < 16; ++j) {
                const int jg = ((j >> 2) << 9) + ub + (j & 3);
                const float* wr = Whh1 + (size_t)jg * HH + k;
                acc[j] = fmaf(hv.x, wr[0], acc[j]);
                acc[j] = fmaf(hv.y, wr[1], acc[j]);
                acc[j] = fmaf(hv.z, wr[2], acc[j]);
                acc[j] = fmaf(hv.w, wr[3], acc[j]);
            }
        }
    }

    __syncthreads();      // biases initialized everywhere before any atomic lands
#pragma unroll
    for (int j = 0; j < 16; ++j) atomicAdd(&gsh[j][lane], acc[j]);
    __syncthreads();

    if (tid < 256) {      // 4 u x 64 b updates, wave-uniform predicate
        const int b  = tid & 63;
        const int ul = tid >> 6;             // 0..3
        const int u  = ub + ul;
        const float iv = sigmoidf_(gsh[ul][b]);
        const float fv = sigmoidf_(gsh[4 + ul][b]);
        const float gv = tanhf(gsh[8 + ul][b]);
        const float ov = sigmoidf_(gsh[12 + ul][b]);
        float* cbuf = layer ? c1 : c0;
        const size_t ci = ((size_t)b << 9) + u;
        const float cn = fv * cbuf[ci] + iv * gv;
        cbuf[ci] = cn;
        const float hn = ov * tanhf(cn);
        float* hTn = layer ? (h1T + (((s - 1) & 1) << 15))
                           : (h0T + ((s & 1) << 15));
        hTn[((size_t)tile << 8) + (b << 2) + ul] = hn;     // hT[u/4][b][u%4]
        if (layer) out[(((size_t)b * TT) + t) * HH + u] = hn;
    }
}

extern "C" void kernel_launch(void* const* d_in, const int* in_sizes, int n_in,
                              void* d_out, int out_size, void* d_ws, size_t ws_size,
                              hipStream_t stream) {
    (void)in_sizes; (void)n_in; (void)out_size; (void)ws_size;
    const float* x    = (const float*)d_in[0];
    const float* Wih0 = (const float*)d_in[1];
    const float* Whh0 = (const float*)d_in[2];
    const float* bi0  = (const float*)d_in[3];
    const float* bh0  = (const float*)d_in[4];
    const float* Wih1 = (const float*)d_in[5];
    const float* Whh1 = (const float*)d_in[6];
    const float* bi1  = (const float*)d_in[7];
    const float* bh1  = (const float*)d_in[8];
    float* out = (float*)d_out;
    float* ws  = (float*)d_ws;

    // ws layout (floats): h0T ping-pong [2][32768] | c0 [32768] | h1T [2][32768] | c1 [32768]
    float* h0T = ws;
    float* c0  = ws + 65536;
    float* h1T = ws + 98304;
    float* c1  = ws + 163840;

    // zero initial h/c state (ws is poisoned 0xAA before every timed call)
    hipMemsetAsync(d_ws, 0, 196608 * sizeof(float), stream);

    for (int s = 0; s <= TT; ++s) {
        lstm_step<<<256, 512, 0, stream>>>(s, x, Wih0, Whh0, bi0, bh0,
                                           Wih1, Whh1, bi1, bh1,
                                           h0T, c0, h1T, c1, out);
    }
}